// Round 14
// baseline (835.058 us; speedup 1.0000x reference)
//
#include <hip/hip_runtime.h>

// 3-layer LSTM, B=256, T=2048, H=32, in=64. fp32.
// r13 structure (6 waves, producer/consumer, 16-step chunks) + serial-chain
// micro-opts: (1) exp2-domain pre-scaled weights (v_exp_f32 used natively,
// no per-step domain muls), (2) depth-4 dot chains, (3) unconditional
// 64-wide ring writes (no exec-mask churn).
//   w3: f0 (chunk p) | w0: rec0 (p-1) | w4: f1 (p-2) | w1: rec1 (p-3)
//   w5: f2 (p-4)     | w2: rec2+proj (p-5)

typedef float v2f __attribute__((ext_vector_type(2)));

constexpr int T_SEQ  = 2048;
constexpr int CH     = 16;
constexpr int NCHUNK = T_SEQ / CH;     // 128
constexpr int NPHASE = NCHUNK + 5;
constexpr float LOG2E  = 1.44269504088896f;
constexpr float TWOL2E = 2.88539008177793f;   // 2*log2(e)

#define GLOAD_LDS16(gsrc, ldst)                                                              \
    __builtin_amdgcn_global_load_lds((const __attribute__((address_space(1))) void*)(gsrc), \
                                     (__attribute__((address_space(3))) void*)(ldst),        \
                                     16, 0, 0)
#define KEEPV(x) asm volatile("" : "+v"(x))

__device__ __forceinline__ float rcp_f(float x) { return __builtin_amdgcn_rcpf(x); }

#if __has_builtin(__builtin_amdgcn_exp2f)
__device__ __forceinline__ float exp2_f(float x) { return __builtin_amdgcn_exp2f(x); }
#else
__device__ __forceinline__ float exp2_f(float x) { return exp2f(x); }
#endif

// returns x[l] + x[l^32] for every lane, via one permlane32_swap (VALU).
__device__ __forceinline__ float swap_sum32(float x) {
#if __has_builtin(__builtin_amdgcn_permlane32_swap)
    auto r = __builtin_amdgcn_permlane32_swap(__float_as_uint(x), __float_as_uint(x),
                                              false, false);
    return __uint_as_float(r[0]) + __uint_as_float(r[1]);
#else
    return x + __shfl_xor(x, 32);
#endif
}

// One chunk of recurrence. Lane l owns gate rows l (A) and l+64 (B):
// l<32 -> A=i, B=g(tanh); l>=32 -> A=f, B=o(sig via tanh half-arg).
// Pre-activations arrive PRE-SCALED: A rows by -log2e, B rows by mt*log2e.
//   sA = rcp(1 + exp2(ga))                 == sigmoid(orig)
//   tb = 1 - 2*rcp(exp2(gb)+1)             == tanh(mt*orig/2)
// hs[32]: wave-uniform h in SGPRs. z: lanes>=32 hold h_new.
template<bool RING>
__device__ __forceinline__ void rec_chunk(int l,
    const v2f* __restrict__ xg_in,        // [CH][64] scaled pre-activations
    float* __restrict__ ring_out,         // [CH][64]; h in slots 32..63
    const v2f (&whA)[16], const v2f (&whB)[16],   // pre-scaled
    float (&hs)[32], float& c, float& z,
    float ca, float cb)
{
    // prefetch the whole chunk's xg into registers (one lgkm batch)
    v2f xgr[CH];
#pragma unroll
    for (int tt = 0; tt < CH; ++tt) xgr[tt] = xg_in[tt * 64 + l];

#pragma unroll
    for (int tt = 0; tt < CH; ++tt) {
        // h-dot: 32 pk_fma, 8 chains of depth 4
        v2f aA[4], aB[4];
        aA[0] = (v2f){xgr[tt].x, 0.f}; aB[0] = (v2f){xgr[tt].y, 0.f};
        aA[1] = (v2f){0.f, 0.f}; aA[2] = aA[1]; aA[3] = aA[1];
        aB[1] = aA[1]; aB[2] = aA[1]; aB[3] = aA[1];
#pragma unroll
        for (int j = 0; j < 16; ++j) {
            const v2f h2 = {hs[2*j], hs[2*j + 1]};
            aA[j & 3] = h2 * whA[j] + aA[j & 3];
            aB[j & 3] = h2 * whB[j] + aB[j & 3];
        }
        const v2f rA = (aA[0] + aA[1]) + (aA[2] + aA[3]);
        const v2f rB = (aB[0] + aB[1]) + (aB[2] + aB[3]);
        const float ga = rA.x + rA.y;
        const float gb = rB.x + rB.y;

        const float sA = rcp_f(1.0f + exp2_f(ga));            // i | f
        const float eb = exp2_f(gb);
        const float tb = fmaf(-2.0f, rcp_f(eb + 1.0f), 1.0f);
        const float vB = fmaf(ca, tb, cb);                    // g | o

        const float p  = sA * ((l < 32) ? vB : c);            // i*g | f*c
        const float cn = swap_sum32(p);                       // c_new, all lanes
        const float ec = exp2_f(cn * TWOL2E);                 // exp(2*cn)
        const float th = fmaf(-2.0f, rcp_f(ec + 1.0f), 1.0f); // tanh(c_new)
        z = vB * th;                                          // lanes>=32: h_new
        c = cn;

        if constexpr (RING) ring_out[tt * 64 + l] = z;        // all lanes, no exec churn

        // h broadcast: 32x readlane from lanes 32..63 -> SGPRs (no DS pipe)
        const int zb = __float_as_int(z);
#pragma unroll
        for (int k = 0; k < 32; ++k)
            hs[k] = __int_as_float(__builtin_amdgcn_readlane(zb, k + 32));
    }
}

// feeder from 64-wide LDS h ring (h in slots 32..63); weights pre-scaled
__device__ __forceinline__ void feed_h_chunk(int l, const float* __restrict__ hr,
    v2f* __restrict__ xg_out, const v2f (&wA)[16], const v2f (&wB)[16],
    float bA, float bB)
{
#pragma unroll
    for (int tt = 0; tt < CH; ++tt) {
        const float4* h4 = reinterpret_cast<const float4*>(hr + tt * 64 + 32);
        v2f a0 = {bA, 0.f}, a1 = {0.f, 0.f}, b0 = {bB, 0.f}, b1 = {0.f, 0.f};
#pragma unroll
        for (int i = 0; i < 8; ++i) {
            const float4 v = h4[i];
            const v2f lo = {v.x, v.y}, hi = {v.z, v.w};
            a0 = lo * wA[2*i] + a0;  a1 = hi * wA[2*i+1] + a1;
            b0 = lo * wB[2*i] + b0;  b1 = hi * wB[2*i+1] + b1;
        }
        xg_out[tt * 64 + l] = (v2f){(a0.x + a1.x) + (a0.y + a1.y),
                                    (b0.x + b1.x) + (b0.y + b1.y)};
    }
}

// feeder layer 0 from staged x (64-wide rows); weights pre-scaled
__device__ __forceinline__ void feed0_chunk(int l, const float* __restrict__ xs,
    v2f* __restrict__ xg_out, const v2f (&wA)[32], const v2f (&wB)[32],
    float bA, float bB)
{
#pragma unroll
    for (int tt = 0; tt < CH; ++tt) {
        const float4* xt = reinterpret_cast<const float4*>(xs + tt * 64);
        v2f a0 = {bA, 0.f}, a1 = {0.f, 0.f}, b0 = {bB, 0.f}, b1 = {0.f, 0.f};
#pragma unroll
        for (int i = 0; i < 16; ++i) {
            const float4 v = xt[i];
            const v2f lo = {v.x, v.y}, hi = {v.z, v.w};
            a0 = lo * wA[2*i] + a0;  a1 = hi * wA[2*i+1] + a1;
            b0 = lo * wB[2*i] + b0;  b1 = hi * wB[2*i+1] + b1;
        }
        xg_out[tt * 64 + l] = (v2f){(a0.x + a1.x) + (a0.y + a1.y),
                                    (b0.x + b1.x) + (b0.y + b1.y)};
    }
}

__global__ __launch_bounds__(384) __attribute__((amdgpu_waves_per_eu(2, 2)))
void lstm3_x2_kernel(const float* __restrict__ x,
    const float* __restrict__ W_ih0, const float* __restrict__ W_hh0, const float* __restrict__ b0,
    const float* __restrict__ W_ih1, const float* __restrict__ W_hh1, const float* __restrict__ b1,
    const float* __restrict__ W_ih2, const float* __restrict__ W_hh2, const float* __restrict__ b2,
    const float* __restrict__ W_out, const float* __restrict__ b_out,
    float* __restrict__ out)
{
    const int bi = blockIdx.x;
    const int w  = threadIdx.x >> 6;
    const int l  = threadIdx.x & 63;

    __shared__ v2f   xg0[2][CH][64];       // 16 KB (scaled pre-acts)
    __shared__ v2f   xg1[2][CH][64];       // 16 KB
    __shared__ v2f   xg2[2][CH][64];       // 16 KB
    __shared__ float h0r[2][CH][64];       // 8 KB (h in slots 32..63)
    __shared__ float h1r[2][CH][64];       // 8 KB
    __shared__ float xstage[2][CH * 64];   // 8 KB

    // per-lane gate-row scale factors (fold exp->exp2 domain into weights)
    const float sclA = -LOG2E;                              // i | f rows
    const float sclB = (l < 32) ? TWOL2E : LOG2E;           // g | o rows
    const float ca   = (l < 32) ? 1.f : 0.5f;
    const float cb   = (l < 32) ? 0.f : 0.5f;

    if (w == 0) {                          // ---- rec0 (chunk p-1) [SIMD0] ----
        __builtin_amdgcn_s_setprio(1);
        v2f whA[16], whB[16];
        const v2f* hA = reinterpret_cast<const v2f*>(W_hh0 + l * 32);
        const v2f* hB = reinterpret_cast<const v2f*>(W_hh0 + (l + 64) * 32);
#pragma unroll
        for (int i = 0; i < 16; ++i) {
            whA[i] = hA[i] * (v2f){sclA, sclA}; KEEPV(whA[i]);
            whB[i] = hB[i] * (v2f){sclB, sclB}; KEEPV(whB[i]);
        }
        float hs[32];
#pragma unroll
        for (int k = 0; k < 32; ++k) hs[k] = 0.f;
        float c = 0.f, z = 0.f;
        __syncthreads();
        for (int p = 0; p < NPHASE; ++p) {
            const int ci = p - 1;
            if (ci >= 0 && ci < NCHUNK)
                rec_chunk<true>(l, &xg0[ci & 1][0][0], &h0r[ci & 1][0][0],
                                whA, whB, hs, c, z, ca, cb);
            __syncthreads();
        }
    } else if (w == 1) {                   // ---- rec1 (chunk p-3) [SIMD1] ----
        __builtin_amdgcn_s_setprio(1);
        v2f whA[16], whB[16];
        const v2f* hA = reinterpret_cast<const v2f*>(W_hh1 + l * 32);
        const v2f* hB = reinterpret_cast<const v2f*>(W_hh1 + (l + 64) * 32);
#pragma unroll
        for (int i = 0; i < 16; ++i) {
            whA[i] = hA[i] * (v2f){sclA, sclA}; KEEPV(whA[i]);
            whB[i] = hB[i] * (v2f){sclB, sclB}; KEEPV(whB[i]);
        }
        float hs[32];
#pragma unroll
        for (int k = 0; k < 32; ++k) hs[k] = 0.f;
        float c = 0.f, z = 0.f;
        __syncthreads();
        for (int p = 0; p < NPHASE; ++p) {
            const int ci = p - 3;
            if (ci >= 0 && ci < NCHUNK)
                rec_chunk<true>(l, &xg1[ci & 1][0][0], &h1r[ci & 1][0][0],
                                whA, whB, hs, c, z, ca, cb);
            __syncthreads();
        }
    } else if (w == 2) {                   // ---- rec2 (chunk p-5) + proj [SIMD2] ----
        __builtin_amdgcn_s_setprio(1);
        v2f whA[16], whB[16];
        const v2f* hA = reinterpret_cast<const v2f*>(W_hh2 + l * 32);
        const v2f* hB = reinterpret_cast<const v2f*>(W_hh2 + (l + 64) * 32);
#pragma unroll
        for (int i = 0; i < 16; ++i) {
            whA[i] = hA[i] * (v2f){sclA, sclA}; KEEPV(whA[i]);
            whB[i] = hB[i] * (v2f){sclB, sclB}; KEEPV(whB[i]);
        }
        const float woutv = W_out[l & 31];
        float hs[32];
#pragma unroll
        for (int k = 0; k < 32; ++k) hs[k] = 0.f;
        float c = 0.f, z = 0.f;
        __syncthreads();
        for (int p = 0; p < NPHASE; ++p) {
            const int ci = p - 5;
            if (ci >= 0 && ci < NCHUNK)
                rec_chunk<false>(l, &xg2[ci & 1][0][0], nullptr,
                                 whA, whB, hs, c, z, ca, cb);
            __syncthreads();
        }
        // h2[T-1] lives in lanes 32..63
        float s = (l >= 32) ? z * woutv : 0.f;
#pragma unroll
        for (int off = 32; off; off >>= 1) s += __shfl_xor(s, off);
        if (l == 0) out[bi] = s + b_out[0];
    } else if (w == 3) {                   // ---- f0: xg0 from x (chunk p) [SIMD3] ----
        v2f wA[32], wB[32];
        const v2f* pA = reinterpret_cast<const v2f*>(W_ih0 + l * 64);
        const v2f* pB = reinterpret_cast<const v2f*>(W_ih0 + (l + 64) * 64);
#pragma unroll
        for (int i = 0; i < 32; ++i) {
            wA[i] = pA[i] * (v2f){sclA, sclA}; KEEPV(wA[i]);
            wB[i] = pB[i] * (v2f){sclB, sclB}; KEEPV(wB[i]);
        }
        const float bAv = b0[l] * sclA, bBv = b0[l + 64] * sclB;
        const float* src = x + (size_t)bi * T_SEQ * 64;
#pragma unroll
        for (int i = 0; i < 4; ++i)
            GLOAD_LDS16(src + i * 256 + l * 4, &xstage[0][i * 256 + l * 4]);
        __syncthreads();                   // drains vmcnt -> chunk 0 resident
        for (int p = 0; p < NPHASE; ++p) {
            if (p + 1 < NCHUNK) {          // prefetch next chunk
                const float* ns = src + (size_t)(p + 1) * CH * 64;
                float* dst = &xstage[(p + 1) & 1][0];
#pragma unroll
                for (int i = 0; i < 4; ++i)
                    GLOAD_LDS16(ns + i * 256 + l * 4, dst + i * 256 + l * 4);
            }
            if (p < NCHUNK)
                feed0_chunk(l, xstage[p & 1], &xg0[p & 1][0][0], wA, wB, bAv, bBv);
            __syncthreads();
        }
    } else if (w == 4) {                   // ---- f1: xg1 from h0 ring (chunk p-2) [SIMD0] ----
        v2f wA[16], wB[16];
        const v2f* pA = reinterpret_cast<const v2f*>(W_ih1 + l * 32);
        const v2f* pB = reinterpret_cast<const v2f*>(W_ih1 + (l + 64) * 32);
#pragma unroll
        for (int i = 0; i < 16; ++i) {
            wA[i] = pA[i] * (v2f){sclA, sclA}; KEEPV(wA[i]);
            wB[i] = pB[i] * (v2f){sclB, sclB}; KEEPV(wB[i]);
        }
        const float bAv = b1[l] * sclA, bBv = b1[l + 64] * sclB;
        __syncthreads();
        for (int p = 0; p < NPHASE; ++p) {
            const int ci = p - 2;
            if (ci >= 0 && ci < NCHUNK)
                feed_h_chunk(l, &h0r[ci & 1][0][0], &xg1[ci & 1][0][0], wA, wB, bAv, bBv);
            __syncthreads();
        }
    } else {                               // ---- f2: xg2 from h1 ring (chunk p-4) [SIMD1] ----
        v2f wA[16], wB[16];
        const v2f* pA = reinterpret_cast<const v2f*>(W_ih2 + l * 32);
        const v2f* pB = reinterpret_cast<const v2f*>(W_ih2 + (l + 64) * 32);
#pragma unroll
        for (int i = 0; i < 16; ++i) {
            wA[i] = pA[i] * (v2f){sclA, sclA}; KEEPV(wA[i]);
            wB[i] = pB[i] * (v2f){sclB, sclB}; KEEPV(wB[i]);
        }
        const float bAv = b2[l] * sclA, bBv = b2[l + 64] * sclB;
        __syncthreads();
        for (int p = 0; p < NPHASE; ++p) {
            const int ci = p - 4;
            if (ci >= 0 && ci < NCHUNK)
                feed_h_chunk(l, &h1r[ci & 1][0][0], &xg2[ci & 1][0][0], wA, wB, bAv, bBv);
            __syncthreads();
        }
    }
}

extern "C" void kernel_launch(void* const* d_in, const int* in_sizes, int n_in,
                              void* d_out, int out_size, void* d_ws, size_t ws_size,
                              hipStream_t stream) {
    const float* x      = (const float*)d_in[0];
    const float* W_ih0  = (const float*)d_in[1];
    const float* W_hh0  = (const float*)d_in[2];
    const float* b0     = (const float*)d_in[3];
    const float* W_ih1  = (const float*)d_in[4];
    const float* W_hh1  = (const float*)d_in[5];
    const float* b1     = (const float*)d_in[6];
    const float* W_ih2  = (const float*)d_in[7];
    const float* W_hh2  = (const float*)d_in[8];
    const float* b2     = (const float*)d_in[9];
    const float* W_out  = (const float*)d_in[10];
    const float* b_out  = (const float*)d_in[11];

    lstm3_x2_kernel<<<256, 384, 0, stream>>>(x,
                                             W_ih0, W_hh0, b0,
                                             W_ih1, W_hh1, b1,
                                             W_ih2, W_hh2, b2,
                                             W_out, b_out,
                                             (float*)d_out);
}

// Round 15
// 686.934 us; speedup vs baseline: 1.2156x; 1.2156x over previous
//
#include <hip/hip_runtime.h>

// 3-layer LSTM, B=256, T=2048, H=32, in=64. fp32.
// EXACT r13 structure (6 waves, producer/consumer, 16-step chunks, readlane
// h-broadcast, permlane32 gate exchange). Single change vs r13: exp2-domain
// pre-scaled weights/biases -> v_exp_f32 (2^x) used natively, removing the
// per-step domain multiplies from the serial recurrence chain.
//   w3: f0 (chunk p) | w0: rec0 (p-1) | w4: f1 (p-2) | w1: rec1 (p-3)
//   w5: f2 (p-4)     | w2: rec2+proj (p-5)

typedef float v2f __attribute__((ext_vector_type(2)));

constexpr int T_SEQ  = 2048;
constexpr int CH     = 16;
constexpr int NCHUNK = T_SEQ / CH;     // 128
constexpr int NPHASE = NCHUNK + 5;
constexpr float LOG2E  = 1.44269504088896f;
constexpr float TWOL2E = 2.88539008177793f;   // 2*log2(e)

#define GLOAD_LDS16(gsrc, ldst)                                                              \
    __builtin_amdgcn_global_load_lds((const __attribute__((address_space(1))) void*)(gsrc), \
                                     (__attribute__((address_space(3))) void*)(ldst),        \
                                     16, 0, 0)
#define KEEPV(x) asm volatile("" : "+v"(x))

__device__ __forceinline__ float rcp_f(float x) { return __builtin_amdgcn_rcpf(x); }

__device__ __forceinline__ float exp2_f(float x) { return __builtin_amdgcn_exp2f(x); }

// returns x[l] + x[l^32] for every lane, via one permlane32_swap (VALU).
__device__ __forceinline__ float swap_sum32(float x) {
#if __has_builtin(__builtin_amdgcn_permlane32_swap)
    auto r = __builtin_amdgcn_permlane32_swap(__float_as_uint(x), __float_as_uint(x),
                                              false, false);
    return __uint_as_float(r[0]) + __uint_as_float(r[1]);
#else
    return x + __shfl_xor(x, 32);
#endif
}

// One chunk of recurrence. Lane l owns gate rows l (A) and l+64 (B):
// l<32 -> A=i, B=g(tanh); l>=32 -> A=f, B=o(sig via tanh half-arg).
// Pre-activations arrive PRE-SCALED: A rows by -log2e, B rows by mt*log2e:
//   sA = rcp(1 + exp2(ga))          == sigmoid(orig_ga)
//   tb = 1 - 2*rcp(exp2(gb) + 1)    == tanh(mt*orig_gb/2)
// hs[32]: wave-uniform h in SGPRs. z: lanes>=32 hold h_new after each step.
template<bool RING>
__device__ __forceinline__ void rec_chunk(int l,
    const v2f* __restrict__ xg_in,        // [CH][64] scaled gate pre-activations
    float* __restrict__ ring_out,         // [CH][32] h chunk to next feeder
    const v2f (&whA)[16], const v2f (&whB)[16],   // pre-scaled
    float (&hs)[32], float& c, float& z,
    float ca, float cb)
{
    // prefetch the whole chunk's xg into registers (one lgkm batch)
    v2f xgr[CH];
#pragma unroll
    for (int tt = 0; tt < CH; ++tt) xgr[tt] = xg_in[tt * 64 + l];

#pragma unroll
    for (int tt = 0; tt < CH; ++tt) {
        // h-dot: 32 pk_fma with wave-uniform (SGPR) h operand, 4 chains
        v2f aA0 = {xgr[tt].x, 0.f}, aA1 = {0.f, 0.f};
        v2f aB0 = {xgr[tt].y, 0.f}, aB1 = {0.f, 0.f};
#pragma unroll
        for (int j = 0; j < 16; j += 2) {
            const v2f h0 = {hs[2*j],     hs[2*j + 1]};
            const v2f h1 = {hs[2*j + 2], hs[2*j + 3]};
            aA0 = h0 * whA[j]     + aA0;
            aB0 = h0 * whB[j]     + aB0;
            aA1 = h1 * whA[j + 1] + aA1;
            aB1 = h1 * whB[j + 1] + aB1;
        }
        const float ga = (aA0.x + aA1.x) + (aA0.y + aA1.y);
        const float gb = (aB0.x + aB1.x) + (aB0.y + aB1.y);

        const float sA = rcp_f(1.0f + exp2_f(ga));            // i | f
        const float eb = exp2_f(gb);
        const float tb = fmaf(-2.0f, rcp_f(eb + 1.0f), 1.0f);
        const float vB = fmaf(ca, tb, cb);                    // g | o

        const float p  = sA * ((l < 32) ? vB : c);            // i*g | f*c
        const float cn = swap_sum32(p);                       // c_new, all lanes
        const float ec = exp2_f(cn * TWOL2E);                 // exp(2*cn)
        const float th = fmaf(-2.0f, rcp_f(ec + 1.0f), 1.0f); // tanh(c_new)
        z = vB * th;                                          // lanes>=32: h_new
        c = cn;

        if constexpr (RING) { if (l >= 32) ring_out[tt * 32 + (l - 32)] = z; }

        // h broadcast: 32x readlane from lanes 32..63 -> SGPRs (no DS pipe)
        const int zb = __float_as_int(z);
#pragma unroll
        for (int k = 0; k < 32; ++k)
            hs[k] = __int_as_float(__builtin_amdgcn_readlane(zb, k + 32));
    }
}

// feeder from 32-wide LDS h ring; weights pre-scaled
__device__ __forceinline__ void feed_h_chunk(int l, const float* __restrict__ hr,
    v2f* __restrict__ xg_out, const v2f (&wA)[16], const v2f (&wB)[16],
    float bA, float bB)
{
#pragma unroll
    for (int tt = 0; tt < CH; ++tt) {
        const float4* h4 = reinterpret_cast<const float4*>(hr + tt * 32);
        v2f a0 = {bA, 0.f}, a1 = {0.f, 0.f}, b0 = {bB, 0.f}, b1 = {0.f, 0.f};
#pragma unroll
        for (int i = 0; i < 8; ++i) {
            const float4 v = h4[i];
            const v2f lo = {v.x, v.y}, hi = {v.z, v.w};
            a0 = lo * wA[2*i] + a0;  a1 = hi * wA[2*i+1] + a1;
            b0 = lo * wB[2*i] + b0;  b1 = hi * wB[2*i+1] + b1;
        }
        xg_out[tt * 64 + l] = (v2f){(a0.x + a1.x) + (a0.y + a1.y),
                                    (b0.x + b1.x) + (b0.y + b1.y)};
    }
}

// feeder layer 0 from staged x (64-wide rows); weights pre-scaled
__device__ __forceinline__ void feed0_chunk(int l, const float* __restrict__ xs,
    v2f* __restrict__ xg_out, const v2f (&wA)[32], const v2f (&wB)[32],
    float bA, float bB)
{
#pragma unroll
    for (int tt = 0; tt < CH; ++tt) {
        const float4* xt = reinterpret_cast<const float4*>(xs + tt * 64);
        v2f a0 = {bA, 0.f}, a1 = {0.f, 0.f}, b0 = {bB, 0.f}, b1 = {0.f, 0.f};
#pragma unroll
        for (int i = 0; i < 16; ++i) {
            const float4 v = xt[i];
            const v2f lo = {v.x, v.y}, hi = {v.z, v.w};
            a0 = lo * wA[2*i] + a0;  a1 = hi * wA[2*i+1] + a1;
            b0 = lo * wB[2*i] + b0;  b1 = hi * wB[2*i+1] + b1;
        }
        xg_out[tt * 64 + l] = (v2f){(a0.x + a1.x) + (a0.y + a1.y),
                                    (b0.x + b1.x) + (b0.y + b1.y)};
    }
}

__global__ __launch_bounds__(384) __attribute__((amdgpu_waves_per_eu(2, 2)))
void lstm3_e2_kernel(const float* __restrict__ x,
    const float* __restrict__ W_ih0, const float* __restrict__ W_hh0, const float* __restrict__ b0,
    const float* __restrict__ W_ih1, const float* __restrict__ W_hh1, const float* __restrict__ b1,
    const float* __restrict__ W_ih2, const float* __restrict__ W_hh2, const float* __restrict__ b2,
    const float* __restrict__ W_out, const float* __restrict__ b_out,
    float* __restrict__ out)
{
    const int bi = blockIdx.x;
    const int w  = threadIdx.x >> 6;
    const int l  = threadIdx.x & 63;

    __shared__ v2f   xg0[2][CH][64];       // 16 KB (scaled pre-acts)
    __shared__ v2f   xg1[2][CH][64];       // 16 KB
    __shared__ v2f   xg2[2][CH][64];       // 16 KB
    __shared__ float h0r[2][CH][32];       // 4 KB
    __shared__ float h1r[2][CH][32];       // 4 KB
    __shared__ float xstage[2][CH * 64];   // 8 KB

    // per-lane gate-row scale factors (exp -> exp2 domain fold)
    const float sclA = -LOG2E;                              // i | f rows
    const float sclB = (l < 32) ? TWOL2E : LOG2E;           // g | o rows
    const float ca   = (l < 32) ? 1.f : 0.5f;
    const float cb   = (l < 32) ? 0.f : 0.5f;

    if (w == 0) {                          // ---- rec0 (chunk p-1) [SIMD0] ----
        __builtin_amdgcn_s_setprio(1);
        v2f whA[16], whB[16];
        const v2f* hA = reinterpret_cast<const v2f*>(W_hh0 + l * 32);
        const v2f* hB = reinterpret_cast<const v2f*>(W_hh0 + (l + 64) * 32);
#pragma unroll
        for (int i = 0; i < 16; ++i) {
            whA[i] = hA[i] * (v2f){sclA, sclA}; KEEPV(whA[i]);
            whB[i] = hB[i] * (v2f){sclB, sclB}; KEEPV(whB[i]);
        }
        float hs[32];
#pragma unroll
        for (int k = 0; k < 32; ++k) hs[k] = 0.f;
        float c = 0.f, z = 0.f;
        __syncthreads();
        for (int p = 0; p < NPHASE; ++p) {
            const int ci = p - 1;
            if (ci >= 0 && ci < NCHUNK)
                rec_chunk<true>(l, &xg0[ci & 1][0][0], &h0r[ci & 1][0][0],
                                whA, whB, hs, c, z, ca, cb);
            __syncthreads();
        }
    } else if (w == 1) {                   // ---- rec1 (chunk p-3) [SIMD1] ----
        __builtin_amdgcn_s_setprio(1);
        v2f whA[16], whB[16];
        const v2f* hA = reinterpret_cast<const v2f*>(W_hh1 + l * 32);
        const v2f* hB = reinterpret_cast<const v2f*>(W_hh1 + (l + 64) * 32);
#pragma unroll
        for (int i = 0; i < 16; ++i) {
            whA[i] = hA[i] * (v2f){sclA, sclA}; KEEPV(whA[i]);
            whB[i] = hB[i] * (v2f){sclB, sclB}; KEEPV(whB[i]);
        }
        float hs[32];
#pragma unroll
        for (int k = 0; k < 32; ++k) hs[k] = 0.f;
        float c = 0.f, z = 0.f;
        __syncthreads();
        for (int p = 0; p < NPHASE; ++p) {
            const int ci = p - 3;
            if (ci >= 0 && ci < NCHUNK)
                rec_chunk<true>(l, &xg1[ci & 1][0][0], &h1r[ci & 1][0][0],
                                whA, whB, hs, c, z, ca, cb);
            __syncthreads();
        }
    } else if (w == 2) {                   // ---- rec2 (chunk p-5) + proj [SIMD2] ----
        __builtin_amdgcn_s_setprio(1);
        v2f whA[16], whB[16];
        const v2f* hA = reinterpret_cast<const v2f*>(W_hh2 + l * 32);
        const v2f* hB = reinterpret_cast<const v2f*>(W_hh2 + (l + 64) * 32);
#pragma unroll
        for (int i = 0; i < 16; ++i) {
            whA[i] = hA[i] * (v2f){sclA, sclA}; KEEPV(whA[i]);
            whB[i] = hB[i] * (v2f){sclB, sclB}; KEEPV(whB[i]);
        }
        const float woutv = W_out[l & 31];
        float hs[32];
#pragma unroll
        for (int k = 0; k < 32; ++k) hs[k] = 0.f;
        float c = 0.f, z = 0.f;
        __syncthreads();
        for (int p = 0; p < NPHASE; ++p) {
            const int ci = p - 5;
            if (ci >= 0 && ci < NCHUNK)
                rec_chunk<false>(l, &xg2[ci & 1][0][0], nullptr,
                                 whA, whB, hs, c, z, ca, cb);
            __syncthreads();
        }
        // h2[T-1] lives in lanes 32..63
        float s = (l >= 32) ? z * woutv : 0.f;
#pragma unroll
        for (int off = 32; off; off >>= 1) s += __shfl_xor(s, off);
        if (l == 0) out[bi] = s + b_out[0];
    } else if (w == 3) {                   // ---- f0: xg0 from x (chunk p) [SIMD3] ----
        v2f wA[32], wB[32];
        const v2f* pA = reinterpret_cast<const v2f*>(W_ih0 + l * 64);
        const v2f* pB = reinterpret_cast<const v2f*>(W_ih0 + (l + 64) * 64);
#pragma unroll
        for (int i = 0; i < 32; ++i) {
            wA[i] = pA[i] * (v2f){sclA, sclA}; KEEPV(wA[i]);
            wB[i] = pB[i] * (v2f){sclB, sclB}; KEEPV(wB[i]);
        }
        const float bAv = b0[l] * sclA, bBv = b0[l + 64] * sclB;
        const float* src = x + (size_t)bi * T_SEQ * 64;
#pragma unroll
        for (int i = 0; i < 4; ++i)
            GLOAD_LDS16(src + i * 256 + l * 4, &xstage[0][i * 256 + l * 4]);
        __syncthreads();                   // drains vmcnt -> chunk 0 resident
        for (int p = 0; p < NPHASE; ++p) {
            if (p + 1 < NCHUNK) {          // prefetch next chunk
                const float* ns = src + (size_t)(p + 1) * CH * 64;
                float* dst = &xstage[(p + 1) & 1][0];
#pragma unroll
                for (int i = 0; i < 4; ++i)
                    GLOAD_LDS16(ns + i * 256 + l * 4, dst + i * 256 + l * 4);
            }
            if (p < NCHUNK)
                feed0_chunk(l, xstage[p & 1], &xg0[p & 1][0][0], wA, wB, bAv, bBv);
            __syncthreads();
        }
    } else if (w == 4) {                   // ---- f1: xg1 from h0 ring (chunk p-2) [SIMD0] ----
        v2f wA[16], wB[16];
        const v2f* pA = reinterpret_cast<const v2f*>(W_ih1 + l * 32);
        const v2f* pB = reinterpret_cast<const v2f*>(W_ih1 + (l + 64) * 32);
#pragma unroll
        for (int i = 0; i < 16; ++i) {
            wA[i] = pA[i] * (v2f){sclA, sclA}; KEEPV(wA[i]);
            wB[i] = pB[i] * (v2f){sclB, sclB}; KEEPV(wB[i]);
        }
        const float bAv = b1[l] * sclA, bBv = b1[l + 64] * sclB;
        __syncthreads();
        for (int p = 0; p < NPHASE; ++p) {
            const int ci = p - 2;
            if (ci >= 0 && ci < NCHUNK)
                feed_h_chunk(l, &h0r[ci & 1][0][0], &xg1[ci & 1][0][0], wA, wB, bAv, bBv);
            __syncthreads();
        }
    } else {                               // ---- f2: xg2 from h1 ring (chunk p-4) [SIMD1] ----
        v2f wA[16], wB[16];
        const v2f* pA = reinterpret_cast<const v2f*>(W_ih2 + l * 32);
        const v2f* pB = reinterpret_cast<const v2f*>(W_ih2 + (l + 64) * 32);
#pragma unroll
        for (int i = 0; i < 16; ++i) {
            wA[i] = pA[i] * (v2f){sclA, sclA}; KEEPV(wA[i]);
            wB[i] = pB[i] * (v2f){sclB, sclB}; KEEPV(wB[i]);
        }
        const float bAv = b2[l] * sclA, bBv = b2[l + 64] * sclB;
        __syncthreads();
        for (int p = 0; p < NPHASE; ++p) {
            const int ci = p - 4;
            if (ci >= 0 && ci < NCHUNK)
                feed_h_chunk(l, &h1r[ci & 1][0][0], &xg2[ci & 1][0][0], wA, wB, bAv, bBv);
            __syncthreads();
        }
    }
}

extern "C" void kernel_launch(void* const* d_in, const int* in_sizes, int n_in,
                              void* d_out, int out_size, void* d_ws, size_t ws_size,
                              hipStream_t stream) {
    const float* x      = (const float*)d_in[0];
    const float* W_ih0  = (const float*)d_in[1];
    const float* W_hh0  = (const float*)d_in[2];
    const float* b0     = (const float*)d_in[3];
    const float* W_ih1  = (const float*)d_in[4];
    const float* W_hh1  = (const float*)d_in[5];
    const float* b1     = (const float*)d_in[6];
    const float* W_ih2  = (const float*)d_in[7];
    const float* W_hh2  = (const float*)d_in[8];
    const float* b2     = (const float*)d_in[9];
    const float* W_out  = (const float*)d_in[10];
    const float* b_out  = (const float*)d_in[11];

    lstm3_e2_kernel<<<256, 384, 0, stream>>>(x,
                                             W_ih0, W_hh0, b0,
                                             W_ih1, W_hh1, b1,
                                             W_ih2, W_hh2, b2,
                                             W_out, b_out,
                                             (float*)d_out);
}